// Round 10
// baseline (555.251 us; speedup 1.0000x reference)
//
#include <hip/hip_runtime.h>
#include <math.h>

// ============================================================================
// ViT block, fp32 in / fp32 out, bf16 internal, fp32 accum.
// B=16, N=1024, D=768, H=12, Hd=64, FF=3072, M=16384.
// r14 (resubmit; previous round was an infra failure, ledger re-audited):
// gemm8 K-loop = m201-style 8-phase schedule (2 K-tiles/iter, 256x256, BK=64,
// 8 waves): per phase {ds_reads; stage 1 half-tile (2 gll16); barrier;
// lgkmcnt(0); setprio(1); 16 MFMA; setprio(0); [vmcnt(4) at ph4/ph8];
// barrier}. Quadrant order (0,0),(0,1),(1,1),(1,0) -> ds_reads 12/4/8/0.
// Staging: ph1,2 A(kb)->buf1 (skip it==0); ph3,4 B(ka+2)->buf0;
// ph5,6 A(ka+2)->buf0; ph7,8 B(ka+3)->buf1. vmcnt(4) keeps 2 newest
// half-tiles in flight; tail drains 0. Hand-verified steady/prologue/tail.
// ============================================================================

typedef unsigned short u16;
typedef __attribute__((ext_vector_type(8))) short bf16x8;
typedef __attribute__((ext_vector_type(4))) float f32x4;

#define MFMA_BF16(a, b, c) __builtin_amdgcn_mfma_f32_16x16x32_bf16((a), (b), (c), 0, 0, 0)
#define WAITV(N) asm volatile("s_waitcnt vmcnt(" #N ")" ::: "memory")
#define WAITLGKM0 asm volatile("s_waitcnt lgkmcnt(0)" ::: "memory")
#define SCHED0 __builtin_amdgcn_sched_barrier(0)
#define EXP2F(x) __builtin_amdgcn_exp2f(x)

// Q pre-scale: (1/sqrt(64)) * log2(e), so QK^T yields S*log2e directly.
#define QSCALE 0.18033688011112042f
// 8 * log2(e): exp2(s' - C8LOG2E) == exp(s - 8)
#define C8LOG2E 11.541560327111707f

__device__ __forceinline__ float bf2f(u16 v) {
    return __uint_as_float(((unsigned)v) << 16);
}
__device__ __forceinline__ u16 f2bf(float f) {  // RNE
    unsigned u = __float_as_uint(f);
    u += 0x7fffu + ((u >> 16) & 1u);
    return (u16)(u >> 16);
}
__device__ __forceinline__ unsigned cvtpk_bf16(float lo, float hi) {
    unsigned r;
    asm volatile("v_cvt_pk_bf16_f32 %0, %1, %2" : "=v"(r) : "v"(lo), "v"(hi));
    return r;
}

// fast GELU: x * sigmoid(1.59576912x + 0.07135482x^3); |err| < ~2e-3
__device__ __forceinline__ float gelu_fast(float v) {
    const float t = v * v;
    const float z = v * (1.5957691216f + 0.0713548162f * t);
    const float e = __expf(-z);
    return v * __builtin_amdgcn_rcpf(1.0f + e);
}

typedef __attribute__((address_space(1))) const void gvoid;
typedef __attribute__((address_space(3))) void lvoid;
__device__ __forceinline__ void gll16(const void* g, void* l) {
    // async global->LDS DMA, 16 B/lane; LDS dest = wave-uniform base + lane*16
    __builtin_amdgcn_global_load_lds((gvoid*)g, (lvoid*)l, 16, 0, 0);
}

// ---------------------------------------------------------------------------
// fp32 -> bf16 cast (weights pre-cast, once per launch)
// ---------------------------------------------------------------------------
__global__ __launch_bounds__(256) void cast32(const float* __restrict__ src,
                                              u16* __restrict__ dst, int n8) {
    const int i = blockIdx.x * 256 + threadIdx.x;
    if (i >= n8) return;
    const float4 a = ((const float4*)src)[2 * i];
    const float4 b = ((const float4*)src)[2 * i + 1];
    bf16x8 r;
    r[0] = (short)f2bf(a.x); r[1] = (short)f2bf(a.y);
    r[2] = (short)f2bf(a.z); r[3] = (short)f2bf(a.w);
    r[4] = (short)f2bf(b.x); r[5] = (short)f2bf(b.y);
    r[6] = (short)f2bf(b.z); r[7] = (short)f2bf(b.w);
    ((bf16x8*)dst)[i] = r;
}

// ---------------------------------------------------------------------------
// LayerNorm (row of 768, 256 threads). fp32 in, bf16 out.
// ---------------------------------------------------------------------------
__global__ __launch_bounds__(256) void ln_kernel(const float* __restrict__ x,
                                                 const float* __restrict__ g,
                                                 const float* __restrict__ b,
                                                 u16* __restrict__ out) {
    const int row = blockIdx.x;
    const int t = threadIdx.x;
    const float* xr = x + (size_t)row * 768;
    float v0 = xr[t], v1 = xr[t + 256], v2 = xr[t + 512];
    float s = v0 + v1 + v2;
    float sq = v0 * v0 + v1 * v1 + v2 * v2;
#pragma unroll
    for (int off = 32; off > 0; off >>= 1) {
        s += __shfl_down(s, off);
        sq += __shfl_down(sq, off);
    }
    __shared__ float red_s[4], red_sq[4], sh_mu, sh_rs;
    const int wave = t >> 6, lane = t & 63;
    if (lane == 0) { red_s[wave] = s; red_sq[wave] = sq; }
    __syncthreads();
    if (t == 0) {
        float S = red_s[0] + red_s[1] + red_s[2] + red_s[3];
        float SQ = red_sq[0] + red_sq[1] + red_sq[2] + red_sq[3];
        float mu = S * (1.0f / 768.0f);
        float var = SQ * (1.0f / 768.0f) - mu * mu;
        sh_mu = mu;
        sh_rs = 1.0f / sqrtf(fmaxf(var, 0.0f) + 1e-6f);
    }
    __syncthreads();
    const float mu = sh_mu, rs = sh_rs;
    u16* orow = out + (size_t)row * 768;
    orow[t]       = f2bf((v0 - mu) * rs * g[t]       + b[t]);
    orow[t + 256] = f2bf((v1 - mu) * rs * g[t + 256] + b[t + 256]);
    orow[t + 512] = f2bf((v2 - mu) * rs * g[t + 512] + b[t + 512]);
}

// ---------------------------------------------------------------------------
// NT GEMM, 128x128 tile, BK=32, 4 waves (kept for non-big fallback).
// ---------------------------------------------------------------------------
template <int EPI, int BF16B>
__global__ __launch_bounds__(256, 2) void gemm2(
        const u16* __restrict__ A, const void* __restrict__ Bv,
        const float* __restrict__ bias, const float* __restrict__ res,
        void* __restrict__ Cv, u16* __restrict__ vtb, int N, int K) {
    __shared__ __align__(16) u16 As[128 * 32];
    __shared__ __align__(16) u16 Bs[128 * 32];
    const int t = threadIdx.x;
    const int wave = t >> 6, lane = t & 63;
    const int quad = lane >> 4, mr = lane & 15;
    const int wm = wave >> 1, wn = wave & 1;
    const int m0 = blockIdx.y * 128;
    const int n0 = blockIdx.x * 128;

    f32x4 acc[4][4];
#pragma unroll
    for (int i = 0; i < 4; i++)
#pragma unroll
        for (int j = 0; j < 4; j++) acc[i][j] = (f32x4){0.f, 0.f, 0.f, 0.f};

    const int seg = wave * 2;
    const int drow = lane >> 2;
    const int dcol = (lane & 3) * 8;
    const int sr = t >> 2, skv = t & 3;

    for (int k0 = 0; k0 < K; k0 += 32) {
#pragma unroll
        for (int c = 0; c < 2; c++) {
            const int rowA = (seg + c) * 16 + drow;
            gll16(A + (size_t)(m0 + rowA) * K + k0 + dcol, &As[(seg + c) * 512]);
        }
        if (BF16B) {
            const u16* Bh = (const u16*)Bv;
#pragma unroll
            for (int c = 0; c < 2; c++) {
                const int rowB = (seg + c) * 16 + drow;
                gll16(Bh + (size_t)(n0 + rowB) * K + k0 + dcol, &Bs[(seg + c) * 512]);
            }
        } else {
            const float* Bf = (const float*)Bv;
#pragma unroll
            for (int half = 0; half < 2; half++) {
                const float* src = Bf + (size_t)(n0 + sr + half * 64) * K + k0 + skv * 8;
                const float4 a = *(const float4*)src;
                const float4 b2 = *(const float4*)(src + 4);
                bf16x8 r;
                r[0] = (short)f2bf(a.x);  r[1] = (short)f2bf(a.y);
                r[2] = (short)f2bf(a.z);  r[3] = (short)f2bf(a.w);
                r[4] = (short)f2bf(b2.x); r[5] = (short)f2bf(b2.y);
                r[6] = (short)f2bf(b2.z); r[7] = (short)f2bf(b2.w);
                *(bf16x8*)&Bs[(sr + half * 64) * 32 + skv * 8] = r;
            }
        }
        __syncthreads();
        bf16x8 af[4], bfr[4];
#pragma unroll
        for (int i = 0; i < 4; i++)
            af[i] = *(const bf16x8*)&As[(wm * 64 + i * 16 + mr) * 32 + quad * 8];
#pragma unroll
        for (int j = 0; j < 4; j++)
            bfr[j] = *(const bf16x8*)&Bs[(wn * 64 + j * 16 + mr) * 32 + quad * 8];
#pragma unroll
        for (int i = 0; i < 4; i++)
#pragma unroll
            for (int j = 0; j < 4; j++)
                acc[i][j] = MFMA_BF16(af[i], bfr[j], acc[i][j]);
        __syncthreads();
    }

#pragma unroll
    for (int i = 0; i < 4; i++) {
#pragma unroll
        for (int r = 0; r < 4; r++) {
            const int m = m0 + wm * 64 + i * 16 + quad * 4 + r;
#pragma unroll
            for (int j = 0; j < 4; j++) {
                const int n = n0 + wn * 64 + j * 16 + mr;
                float v = acc[i][j][r] + bias[n];
                if (EPI == 1) {
                    v = gelu_fast(v);
                    ((u16*)Cv)[(size_t)m * N + n] = f2bf(v);
                } else if (EPI == 2) {
                    v += res[(size_t)m * N + n];
                    ((float*)Cv)[(size_t)m * N + n] = v;
                } else {  // EPI == 3: qkv split
                    if (n < 1536) {
                        const float vq = (n < 768) ? v * QSCALE : v;
                        ((u16*)Cv)[(size_t)m * 1536 + n] = f2bf(vq);
                    } else {
                        const int h = (n - 1536) >> 6, hd = (n - 1536) & 63;
                        const int bb = m >> 10, pos = m & 1023;
                        vtb[((size_t)(bb * 12 + h) * 64 + hd) * 1024 + pos] = f2bf(v);
                    }
                }
            }
        }
    }
}

// ---------------------------------------------------------------------------
// gemm8: NT GEMM, 256x256 tile, BK=64, 8 waves (2M x 4N), dbuf LDS (128 KiB),
// m201-style 8-phase schedule (see header). T2 swizzle, XCD-chunked swizzle.
// EPI 1/2: operands swapped (bfv,af) -> C^T fragment -> vectorized stores.
// EPI 3: original order + split epilogues (q/k scalar, V LDS-transpose).
// Requires K % 128 == 0, M,N % 256 == 0, grid % 8 == 0.
// ---------------------------------------------------------------------------
#define AFRAG(T, ROW, KS) \
    (*(const bf16x8*)&(T)[(ROW)][(((((KS) << 2) | quad)) ^ ((ROW) & 7)) << 3])

#define ACCUM(ACCEL, AF, BF)                                  \
    do {                                                      \
        if (EPI == 3) (ACCEL) = MFMA_BF16((AF), (BF), (ACCEL)); \
        else          (ACCEL) = MFMA_BF16((BF), (AF), (ACCEL)); \
    } while (0)

// One phase: optional A/B subtile reads, one half-tile stage, barrier,
// lgkm(0), setprio-wrapped 16 MFMA (quadrant RH,CH x K=64), optional wait,
// end barrier.
#define PHASE(BI, RH, CH, DO_RA, DO_RB, STAGES, WAITS)                          \
    do {                                                                        \
        if (DO_RA) {                                                            \
            _Pragma("unroll") for (int rb = 0; rb < 4; rb++)                    \
                _Pragma("unroll") for (int kk = 0; kk < 2; kk++)                \
                    af[rb * 2 + kk] =                                           \
                        AFRAG(As[BI], wm * 128 + (RH) * 64 + rb * 16 + mr, kk); \
        }                                                                       \
        if (DO_RB) {                                                            \
            _Pragma("unroll") for (int cb = 0; cb < 2; cb++)                    \
                _Pragma("unroll") for (int kk = 0; kk < 2; kk++)                \
                    bc[CH][cb * 2 + kk] =                                       \
                        AFRAG(Bs[BI], wn * 64 + (CH) * 32 + cb * 16 + mr, kk);  \
        }                                                                       \
        STAGES;                                                                 \
        SCHED0;                                                                 \
        __builtin_amdgcn_s_barrier();                                           \
        WAITLGKM0;                                                              \
        SCHED0;                                                                 \
        __builtin_amdgcn_s_setprio(1);                                          \
        _Pragma("unroll") for (int rb = 0; rb < 4; rb++)                        \
            _Pragma("unroll") for (int cb = 0; cb < 2; cb++) {                  \
                ACCUM(acc[(RH) * 4 + rb][(CH) * 2 + cb], af[rb * 2 + 0],        \
                      bc[CH][cb * 2 + 0]);                                      \
                ACCUM(acc[(RH) * 4 + rb][(CH) * 2 + cb], af[rb * 2 + 1],        \
                      bc[CH][cb * 2 + 1]);                                      \
            }                                                                   \
        __builtin_amdgcn_s_setprio(0);                                          \
        SCHED0;                                                                 \
        WAITS;                                                                  \
        __builtin_amdgcn_s_barrier();                                           \
        SCHED0;                                                                 \
    } while (0)

template <int EPI>
__global__ __launch_bounds__(512, 2) void gemm8(
        const u16* __restrict__ A, const u16* __restrict__ Bw,
        const float* __restrict__ bias, const float* __restrict__ res,
        void* __restrict__ Cv, u16* __restrict__ vtb, int N, int K) {
    __shared__ __align__(16) u16 SMEM[4][256][64];  // As=SMEM[0..1], Bs=SMEM[2..3]
    u16(&As)[2][256][64] = *reinterpret_cast<u16(*)[2][256][64]>(&SMEM[0][0][0]);
    u16(&Bs)[2][256][64] = *reinterpret_cast<u16(*)[2][256][64]>(&SMEM[2][0][0]);
    const int t = threadIdx.x;
    const int wave = t >> 6, lane = t & 63;
    const int quad = lane >> 4, mr = lane & 15;
    const int wm = wave >> 2, wn = wave & 3;
    // XCD-chunked bijective swizzle: consecutive remapped ids share the A panel
    const int gx = gridDim.x;
    const int nwg = gx * gridDim.y;
    int bid = blockIdx.y * gx + blockIdx.x;
    bid = (bid & 7) * (nwg >> 3) + (bid >> 3);
    const int m0 = (bid / gx) * 256, n0 = (bid % gx) * 256;
    const int NT = K >> 6;      // K-tiles (even; >= 2)
    const int NI = NT >> 1;     // iterations (2 K-tiles each)

    const int srow = wave * 8 + (lane >> 3);          // row within 64-row slot
    const int sgrp = ((lane & 7) ^ (lane >> 3)) * 8;  // pre-swizzled src col

    const u16* Abase = A + (size_t)(m0 + srow) * K + sgrp;
    const u16* Bbase = Bw + (size_t)(n0 + srow) * K + sgrp;

#define STAGE_A(BI, SLOT, KT) \
    gll16(Abase + ((size_t)(SLOT) * 64) * K + (KT) * 64, &As[BI][(SLOT) * 64 + wave * 8][0])
#define STAGE_B(BI, SLOT, KT) \
    gll16(Bbase + ((size_t)(SLOT) * 64) * K + (KT) * 64, &Bs[BI][(SLOT) * 64 + wave * 8][0])

    // prologue: tiles 0 and 1 fully staged (16 gll16/wave); tile0 landed.
    STAGE_A(0, 0, 0); STAGE_A(0, 1, 0); STAGE_A(0, 2, 0); STAGE_A(0, 3, 0);
    STAGE_B(0, 0, 0); STAGE_B(0, 1, 0); STAGE_B(0, 2, 0); STAGE_B(0, 3, 0);
    STAGE_A(1, 0, 1); STAGE_A(1, 1, 1); STAGE_A(1, 2, 1); STAGE_A(1, 3, 1);
    STAGE_B(1, 0, 1); STAGE_B(1, 1, 1); STAGE_B(1, 2, 1); STAGE_B(1, 3, 1);

    f32x4 acc[8][4];
#pragma unroll
    for (int i = 0; i < 8; i++)
#pragma unroll
        for (int j = 0; j < 4; j++) acc[i][j] = (f32x4){0.f, 0.f, 0.f, 0.f};

    WAITV(8);  // tile0's 8 half-tile loads landed; tile1's 8 in flight
    __builtin_amdgcn_s_barrier();
    SCHED0;

    bf16x8 af[8], bc[2][4];

    for (int it = 0; it < NI; ++it) {
        const int ka = it * 2;               // buf 0
        const int kb = ka + 1;               // buf 1
        const bool s2 = (ka + 2 < NT);
        const bool s3 = (ka + 3 < NT);

        // ---- tile ka (buf 0): phases 1-4 ----
        PHASE(0, 0, 0, 1, 1,
              { if (it) { STAGE_A(1, 0, kb); STAGE_A(1, 1, kb); } }, {});
        PHASE(0, 0, 1, 0, 1,
              { if (it) { STAGE_A(1, 2, kb); STAGE_A(1, 3, kb); } }, {});
        PHASE(0, 1, 1, 1, 0,
              { if (s2) { STAGE_B(0, 0, ka + 2); STAGE_B(0, 1, ka + 2); } }, {});
        PHASE(0, 1, 0, 0, 0,
              { if (s2) { STAGE_B(0, 2, ka + 2); STAGE_B(0, 3, ka + 2); } },
              { if (s2) { WAITV(4); } else { WAITV(0); } });

        // ---- tile kb (buf 1): phases 5-8 ----
        PHASE(1, 0, 0, 1, 1,
              { if (s2) { STAGE_A(0, 0, ka + 2); STAGE_A(0, 1, ka + 2); } }, {});
        PHASE(1, 0, 1, 0, 1,
              { if (s2) { STAGE_A(0, 2, ka + 2); STAGE_A(0, 3, ka + 2); } }, {});
        PHASE(1, 1, 1, 1, 0,
              { if (s3) { STAGE_B(1, 0, ka + 3); STAGE_B(1, 1, ka + 3); } }, {});
        PHASE(1, 1, 0, 0, 0,
              { if (s3) { STAGE_B(1, 2, ka + 3); STAGE_B(1, 3, ka + 3); } },
              { if (s3) { WAITV(4); } else { WAITV(0); } });
    }

    if (EPI == 3) {
        if (n0 >= 1536) {
            // V-epilogue: LDS transpose (Ls[n_local][m swizzled]) -> coalesced vtb
            u16* Ls = &SMEM[0][0][0];  // 65536 u16 = [256 n][256 m]
            __syncthreads();
#pragma unroll
            for (int i = 0; i < 8; i++) {
                const int mbase = wm * 128 + (i >> 2) * 64 + (i & 3) * 16 + quad * 4;
                const int mch = mbase >> 3, mlo = mbase & 7;  // mlo in {0,4}
#pragma unroll
                for (int j = 0; j < 4; j++) {
                    const int nl = wn * 64 + j * 16 + mr;
                    float v0 = acc[i][j][0] + bias[n0 + nl];
                    float v1 = acc[i][j][1] + bias[n0 + nl];
                    float v2 = acc[i][j][2] + bias[n0 + nl];
                    float v3 = acc[i][j][3] + bias[n0 + nl];
                    ushort4 w;
                    w.x = f2bf(v0); w.y = f2bf(v1); w.z = f2bf(v2); w.w = f2bf(v3);
                    *(ushort4*)(Ls + nl * 256 + ((mch ^ (nl & 7)) << 3) + mlo) = w;
                }
            }
            __syncthreads();
            const int bb = m0 >> 10, pos0 = m0 & 1023;
#pragma unroll
            for (int it2 = 0; it2 < 32; it2++) {
                const int nl = it2 * 8 + wave;  // wave-uniform column
                const int h = (n0 - 1536 + nl) >> 6;
                const int hd = nl & 63;
                const int mch = (lane >> 1) ^ (nl & 7);
                const ushort4 v =
                    *(const ushort4*)(Ls + nl * 256 + (mch << 3) + (lane & 1) * 4);
                u16* dst = vtb + ((size_t)(bb * 12 + h) * 64 + hd) * 1024 + pos0 + lane * 4;
                *(ushort4*)dst = v;  // 512B contiguous per wave
            }
        } else {
            // q/k region: scalar epilogue (r = m-direction)
#pragma unroll
            for (int i = 0; i < 8; i++) {
#pragma unroll
                for (int r = 0; r < 4; r++) {
                    const int m = m0 + wm * 128 + (i >> 2) * 64 + (i & 3) * 16 + quad * 4 + r;
#pragma unroll
                    for (int j = 0; j < 4; j++) {
                        const int n = n0 + wn * 64 + j * 16 + mr;
                        float v = acc[i][j][r] + bias[n];
                        const float vq = (n < 768) ? v * QSCALE : v;
                        ((u16*)Cv)[(size_t)m * 1536 + n] = f2bf(vq);
                    }
                }
            }
        }
    } else {
        // swapped fragment: lane holds n..n+3 (reg r) at fixed m
#pragma unroll
        for (int ii = 0; ii < 8; ii++) {
            const int m = m0 + wm * 128 + (ii >> 2) * 64 + (ii & 3) * 16 + mr;
#pragma unroll
            for (int j = 0; j < 4; j++) {
                const int n = n0 + wn * 64 + j * 16 + quad * 4;
                const float4 b4 = *(const float4*)&bias[n];
                const float v0 = acc[ii][j][0] + b4.x;
                const float v1 = acc[ii][j][1] + b4.y;
                const float v2 = acc[ii][j][2] + b4.z;
                const float v3 = acc[ii][j][3] + b4.w;
                if (EPI == 1) {
                    ushort4 w;
                    w.x = f2bf(gelu_fast(v0)); w.y = f2bf(gelu_fast(v1));
                    w.z = f2bf(gelu_fast(v2)); w.w = f2bf(gelu_fast(v3));
                    *(ushort4*)&((u16*)Cv)[(size_t)m * N + n] = w;
                } else {  // EPI == 2
                    const float4 r4 = *(const float4*)&res[(size_t)m * N + n];
                    float4 o;
                    o.x = v0 + r4.x; o.y = v1 + r4.y; o.z = v2 + r4.z; o.w = v3 + r4.w;
                    *(float4*)&((float*)Cv)[(size_t)m * N + n] = o;
                }
            }
        }
    }
#undef STAGE_A
#undef STAGE_B
}

// ---------------------------------------------------------------------------
// Flash attention v2. Block = (b,h) x 64 q-rows, 4 waves x 16 rows.
// qkkb [M][1536]: q(pre-scaled QSCALE=0.125*log2e) @0, k @768.
// vtb [b*12+h][64 hd][1024].
// Swapped-operand MFMA; exp2 softmax; cvt_pk P pack; O^T fragment.
// XCD remap: dispatch-linear L, xcd=L&7 -> bh in [xcd*24, xcd*24+24).
// ---------------------------------------------------------------------------
__global__ __launch_bounds__(256) void attn2(const u16* __restrict__ qkkb,
                                             const u16* __restrict__ vtb,
                                             u16* __restrict__ ctx) {
    __shared__ __align__(16) u16 Ks[2][64][72];
    __shared__ __align__(16) u16 Vt[2][64][72];
    __shared__ __align__(16) u16 Ps[64][72];
    const int L = blockIdx.y * gridDim.x + blockIdx.x;  // dispatch-linear
    const int lxcd = L & 7, li = L >> 3;                // li in [0,384)
    const int bh = lxcd * 24 + (li >> 4);
    const int q0 = (li & 15) * 64;
    const int b = bh / 12, h = bh % 12;
    const int t = threadIdx.x;
    const int wave = t >> 6, lane = t & 63, quad = lane >> 4, mr = lane & 15;

    const u16* qrow = qkkb + (size_t)(b * 1024 + q0 + wave * 16 + mr) * 1536 + h * 64;
    const bf16x8 qf0 = *(const bf16x8*)(qrow + quad * 8);
    const bf16x8 qf1 = *(const bf16x8*)(qrow + 32 + quad * 8);

    const u16* kbase = qkkb + (size_t)b * 1024 * 1536 + 768 + h * 64;
    const u16* vbase = vtb + (size_t)bh * 64 * 1024;

    const int srow = t >> 3;  // 0..31 (two halves: +0, +32)
    const int sv = t & 7;     // 16B chunk

    f32x4 oacc[4];
#pragma unroll
    for (int j = 0; j < 4; j++) oacc[j] = (f32x4){0.f, 0.f, 0.f, 0.f};
    float lsum = 0.f;  // q = mr, kv subset = lane's quads

    bf16x8 pk0, pk1, pv0, pv1;
    pk0 = *(const bf16x8*)(kbase + (size_t)(srow)      * 1536 + sv * 8);
    pk1 = *(const bf16x8*)(kbase + (size_t)(srow + 32) * 1536 + sv * 8);
    pv0 = *(const bf16x8*)(vbase + (size_t)(srow)      * 1024 + sv * 8);
    pv1 = *(const bf16x8*)(vbase + (size_t)(srow + 32) * 1024 + sv * 8);
    *(bf16x8*)&Ks[0][srow][sv * 8] = pk0;
    *(bf16x8*)&Ks[0][srow + 32][sv * 8] = pk1;
    *(bf16x8*)&Vt[0][srow][sv * 8] = pv0;
    *(bf16x8*)&Vt[0][srow + 32][sv * 8] = pv1;

    for (int kt = 0; kt < 16; ++kt) {
        __syncthreads();
        const int cur = kt & 1;
        if (kt < 15) {
            const size_t ko = (size_t)(kt + 1) * 64;
            pk0 = *(const bf16x8*)(kbase + (ko + srow)      * 1536 + sv * 8);
            pk1 = *(const bf16x8*)(kbase + (ko + srow + 32) * 1536 + sv * 8);
            pv0 = *(const bf16x8*)(vbase + (size_t)(srow)      * 1024 + ko + sv * 8);
            pv1 = *(const bf16x8*)(vbase + (size_t)(srow + 32) * 1024 + ko + sv * 8);
        }
        // S^T = K Q^T: lane holds S[q=mr][kv=j*16+quad*4+r] (scale in Q)
        f32x4 sf[4];
#pragma unroll
        for (int j = 0; j < 4; j++) {
            const bf16x8 kf0 = *(const bf16x8*)&Ks[cur][j * 16 + mr][quad * 8];
            const bf16x8 kf1 = *(const bf16x8*)&Ks[cur][j * 16 + mr][32 + quad * 8];
            f32x4 s = (f32x4){0.f, 0.f, 0.f, 0.f};
            s = MFMA_BF16(kf0, qf0, s);
            s = MFMA_BF16(kf1, qf1, s);
            sf[j] = s;
        }
        // p = exp2(s' - 8*log2e) == exp(s - 8); pack pairs, 1 b64 write per j
#pragma unroll
        for (int j = 0; j < 4; j++) {
            const float p0 = EXP2F(sf[j][0] - C8LOG2E);
            const float p1 = EXP2F(sf[j][1] - C8LOG2E);
            const float p2 = EXP2F(sf[j][2] - C8LOG2E);
            const float p3 = EXP2F(sf[j][3] - C8LOG2E);
            lsum += (p0 + p1) + (p2 + p3);
            uint2 w;
            w.x = cvtpk_bf16(p0, p1);
            w.y = cvtpk_bf16(p2, p3);
            *(uint2*)&Ps[wave * 16 + mr][j * 16 + quad * 4] = w;
        }
        __asm__ __volatile__("s_waitcnt lgkmcnt(0)" ::: "memory");  // wave-local Ps RAW
        // O^T += V P^T  (A = V^T rows=d, B = P rows=q)
#pragma unroll
        for (int st = 0; st < 2; st++) {
            const bf16x8 pf = *(const bf16x8*)&Ps[wave * 16 + mr][st * 32 + quad * 8];
#pragma unroll
            for (int j = 0; j < 4; j++) {
                const bf16x8 vf = *(const bf16x8*)&Vt[cur][j * 16 + mr][st * 32 + quad * 8];
                oacc[j] = MFMA_BF16(vf, pf, oacc[j]);
            }
        }
        if (kt < 15) {
            const int nxt = cur ^ 1;
            *(bf16x8*)&Ks[nxt][srow][sv * 8] = pk0;
            *(bf16x8*)&Ks[nxt][srow + 32][sv * 8] = pk1;
            *(bf16x8*)&Vt[nxt][srow][sv * 8] = pv0;
            *(bf16x8*)&Vt[nxt][srow + 32][sv * 8] = pv1;
        }
    }

    // lsum: reduce across the 4 quads (same q=mr)
    lsum += __shfl_xor(lsum, 16);
    lsum += __shfl_xor(lsum, 32);
    const float inv = 1.0f / lsum;
    // lane holds O[d=j*16+quad*4+r][q=mr]: 4 contiguous d per j -> ushort4
    u16* dst = ctx + (size_t)(b * 1024 + q0 + wave * 16 + mr) * 768 + h * 64;
#pragma unroll
    for (int j = 0; j < 4; j++) {
        ushort4 w;
        w.x = f2bf(oacc[j][0] * inv);
        w.y = f2bf(oacc[j][1] * inv);
        w.z = f2bf(oacc[j][2] * inv);
        w.w = f2bf(oacc[j][3] * inv);
        *(ushort4*)(dst + j * 16 + quad * 4) = w;
    }
}

// ---------------------------------------------------------------------------
// Launcher. ws layout (bytes), base = d_ws + 1024:
//   xn/ctxb/hn @ +0         (25165824)
//   qkkb       @ +25165824  (50331648)  } h1 (100663296) overlays both
//   vtb        @ +75497472  (25165824)  } (dead after attention)
// bf16 weights (14155776 B) appended iff ws_size >= 139,985,920; else the
// GEMMs fall back to in-staging fp32->bf16 B casts (gemm2 path).
// ---------------------------------------------------------------------------
extern "C" void kernel_launch(void* const* d_in, const int* in_sizes, int n_in,
                              void* d_out, int out_size, void* d_ws, size_t ws_size,
                              hipStream_t stream) {
    const float* x      = (const float*)d_in[0];
    const float* ln1_g  = (const float*)d_in[1];
    const float* ln1_b  = (const float*)d_in[2];
    const float* qkv_w  = (const float*)d_in[3];
    const float* qkv_b  = (const float*)d_in[4];
    const float* proj_w = (const float*)d_in[5];
    const float* proj_b = (const float*)d_in[6];
    const float* ln2_g  = (const float*)d_in[7];
    const float* ln2_b  = (const float*)d_in[8];
    const float* fc1_w  = (const float*)d_in[9];
    const float* fc1_b  = (const float*)d_in[10];
    const float* fc2_w  = (const float*)d_in[11];
    const float* fc2_b  = (const float*)d_in[12];
    float* out = (float*)d_out;

    char* base = (char*)d_ws + 1024;
    u16* xn   = (u16*)base;                  // reused: ctxb, hn
    u16* qkkb = (u16*)(base + 25165824);
    u16* vtb  = (u16*)(base + 75497472);
    u16* h1   = (u16*)(base + 25165824);     // overlays qkkb+vtb
    u16* ctxb = xn;
    u16* hn   = xn;

    const size_t WOFF = 125830144ull;
    const bool big = ws_size >= 139985920ull;
    u16* wqkv  = (u16*)((char*)d_ws + WOFF);
    u16* wproj = (u16*)((char*)d_ws + WOFF + 3538944);
    u16* wfc1  = (u16*)((char*)d_ws + WOFF + 4718592);
    u16* wfc2  = (u16*)((char*)d_ws + WOFF + 9437184);

    if (big) {
        cast32<<<dim3(864),  dim3(256), 0, stream>>>(qkv_w,  wqkv,  221184);
        cast32<<<dim3(288),  dim3(256), 0, stream>>>(proj_w, wproj, 73728);
        cast32<<<dim3(1152), dim3(256), 0, stream>>>(fc1_w,  wfc1,  294912);
        cast32<<<dim3(1152), dim3(256), 0, stream>>>(fc2_w,  wfc2,  294912);
    }

    ln_kernel<<<dim3(16384), dim3(256), 0, stream>>>(x, ln1_g, ln1_b, xn);

    if (big)
        gemm8<3><<<dim3(9, 64), dim3(512), 0, stream>>>(
            xn, wqkv, qkv_b, nullptr, qkkb, vtb, 2304, 768);
    else
        gemm2<3, 0><<<dim3(18, 128), dim3(256), 0, stream>>>(
            xn, qkv_w, qkv_b, nullptr, qkkb, vtb, 2304, 768);

    attn2<<<dim3(16, 192), dim3(256), 0, stream>>>(qkkb, vtb, ctxb);

    if (big)
        gemm8<2><<<dim3(3, 64), dim3(512), 0, stream>>>(
            ctxb, wproj, proj_b, x, out, nullptr, 768, 768);
    else
        gemm2<2, 0><<<dim3(6, 128), dim3(256), 0, stream>>>(
            ctxb, proj_w, proj_b, x, out, nullptr, 768, 768);

    ln_kernel<<<dim3(16384), dim3(256), 0, stream>>>(out, ln2_g, ln2_b, hn);

    if (big)
        gemm8<1><<<dim3(12, 64), dim3(512), 0, stream>>>(
            hn, wfc1, fc1_b, nullptr, h1, nullptr, 3072, 768);
    else
        gemm2<1, 0><<<dim3(24, 128), dim3(256), 0, stream>>>(
            hn, fc1_w, fc1_b, nullptr, h1, nullptr, 3072, 768);

    if (big)
        gemm8<2><<<dim3(3, 64), dim3(512), 0, stream>>>(
            h1, wfc2, fc2_b, out, out, nullptr, 768, 3072);
    else
        gemm2<2, 0><<<dim3(6, 128), dim3(256), 0, stream>>>(
            h1, fc2_w, fc2_b, out, out, nullptr, 768, 3072);
}

// Round 11
// 504.793 us; speedup vs baseline: 1.1000x; 1.1000x over previous
//
#include <hip/hip_runtime.h>
#include <math.h>

// ============================================================================
// ViT block, fp32 in / fp32 out, bf16 internal, fp32 accum.
// B=16, N=1024, D=768, H=12, Hd=64, FF=3072, M=16384.
// r15 = r13 revert (free-flow gemm8; 8-phase r14 regressed 105.8->129us) +
// attn2 Q-block 64->128 (8 waves/512 thr): K/V staging amortized over 2x Q
// rows (total staging halves), 1536 blocks = 6 exact rounds, LDS 55KB ->
// 2 blocks/CU = 4 waves/SIMD. Per-wave compute + softmax path unchanged.
// ============================================================================

typedef unsigned short u16;
typedef __attribute__((ext_vector_type(8))) short bf16x8;
typedef __attribute__((ext_vector_type(4))) float f32x4;

#define MFMA_BF16(a, b, c) __builtin_amdgcn_mfma_f32_16x16x32_bf16((a), (b), (c), 0, 0, 0)
#define WAITV(N) asm volatile("s_waitcnt vmcnt(" #N ")" ::: "memory")
#define WAITLGKM0 asm volatile("s_waitcnt lgkmcnt(0)" ::: "memory")
#define SCHED0 __builtin_amdgcn_sched_barrier(0)
#define EXP2F(x) __builtin_amdgcn_exp2f(x)

// Q pre-scale: (1/sqrt(64)) * log2(e), so QK^T yields S*log2e directly.
#define QSCALE 0.18033688011112042f
// 8 * log2(e): exp2(s' - C8LOG2E) == exp(s - 8)
#define C8LOG2E 11.541560327111707f

__device__ __forceinline__ float bf2f(u16 v) {
    return __uint_as_float(((unsigned)v) << 16);
}
__device__ __forceinline__ u16 f2bf(float f) {  // RNE
    unsigned u = __float_as_uint(f);
    u += 0x7fffu + ((u >> 16) & 1u);
    return (u16)(u >> 16);
}
__device__ __forceinline__ unsigned cvtpk_bf16(float lo, float hi) {
    unsigned r;
    asm volatile("v_cvt_pk_bf16_f32 %0, %1, %2" : "=v"(r) : "v"(lo), "v"(hi));
    return r;
}

// fast GELU: x * sigmoid(1.59576912x + 0.07135482x^3); |err| < ~2e-3
__device__ __forceinline__ float gelu_fast(float v) {
    const float t = v * v;
    const float z = v * (1.5957691216f + 0.0713548162f * t);
    const float e = __expf(-z);
    return v * __builtin_amdgcn_rcpf(1.0f + e);
}

typedef __attribute__((address_space(1))) const void gvoid;
typedef __attribute__((address_space(3))) void lvoid;
__device__ __forceinline__ void gll16(const void* g, void* l) {
    // async global->LDS DMA, 16 B/lane; LDS dest = wave-uniform base + lane*16
    __builtin_amdgcn_global_load_lds((gvoid*)g, (lvoid*)l, 16, 0, 0);
}

// ---------------------------------------------------------------------------
// fp32 -> bf16 cast (weights pre-cast, once per launch)
// ---------------------------------------------------------------------------
__global__ __launch_bounds__(256) void cast32(const float* __restrict__ src,
                                              u16* __restrict__ dst, int n8) {
    const int i = blockIdx.x * 256 + threadIdx.x;
    if (i >= n8) return;
    const float4 a = ((const float4*)src)[2 * i];
    const float4 b = ((const float4*)src)[2 * i + 1];
    bf16x8 r;
    r[0] = (short)f2bf(a.x); r[1] = (short)f2bf(a.y);
    r[2] = (short)f2bf(a.z); r[3] = (short)f2bf(a.w);
    r[4] = (short)f2bf(b.x); r[5] = (short)f2bf(b.y);
    r[6] = (short)f2bf(b.z); r[7] = (short)f2bf(b.w);
    ((bf16x8*)dst)[i] = r;
}

// ---------------------------------------------------------------------------
// LayerNorm (row of 768, 256 threads). fp32 in, bf16 out.
// ---------------------------------------------------------------------------
__global__ __launch_bounds__(256) void ln_kernel(const float* __restrict__ x,
                                                 const float* __restrict__ g,
                                                 const float* __restrict__ b,
                                                 u16* __restrict__ out) {
    const int row = blockIdx.x;
    const int t = threadIdx.x;
    const float* xr = x + (size_t)row * 768;
    float v0 = xr[t], v1 = xr[t + 256], v2 = xr[t + 512];
    float s = v0 + v1 + v2;
    float sq = v0 * v0 + v1 * v1 + v2 * v2;
#pragma unroll
    for (int off = 32; off > 0; off >>= 1) {
        s += __shfl_down(s, off);
        sq += __shfl_down(sq, off);
    }
    __shared__ float red_s[4], red_sq[4], sh_mu, sh_rs;
    const int wave = t >> 6, lane = t & 63;
    if (lane == 0) { red_s[wave] = s; red_sq[wave] = sq; }
    __syncthreads();
    if (t == 0) {
        float S = red_s[0] + red_s[1] + red_s[2] + red_s[3];
        float SQ = red_sq[0] + red_sq[1] + red_sq[2] + red_sq[3];
        float mu = S * (1.0f / 768.0f);
        float var = SQ * (1.0f / 768.0f) - mu * mu;
        sh_mu = mu;
        sh_rs = 1.0f / sqrtf(fmaxf(var, 0.0f) + 1e-6f);
    }
    __syncthreads();
    const float mu = sh_mu, rs = sh_rs;
    u16* orow = out + (size_t)row * 768;
    orow[t]       = f2bf((v0 - mu) * rs * g[t]       + b[t]);
    orow[t + 256] = f2bf((v1 - mu) * rs * g[t + 256] + b[t + 256]);
    orow[t + 512] = f2bf((v2 - mu) * rs * g[t + 512] + b[t + 512]);
}

// ---------------------------------------------------------------------------
// NT GEMM, 128x128 tile, BK=32, 4 waves (kept for non-big fallback).
// ---------------------------------------------------------------------------
template <int EPI, int BF16B>
__global__ __launch_bounds__(256, 2) void gemm2(
        const u16* __restrict__ A, const void* __restrict__ Bv,
        const float* __restrict__ bias, const float* __restrict__ res,
        void* __restrict__ Cv, u16* __restrict__ vtb, int N, int K) {
    __shared__ __align__(16) u16 As[128 * 32];
    __shared__ __align__(16) u16 Bs[128 * 32];
    const int t = threadIdx.x;
    const int wave = t >> 6, lane = t & 63;
    const int quad = lane >> 4, mr = lane & 15;
    const int wm = wave >> 1, wn = wave & 1;
    const int m0 = blockIdx.y * 128;
    const int n0 = blockIdx.x * 128;

    f32x4 acc[4][4];
#pragma unroll
    for (int i = 0; i < 4; i++)
#pragma unroll
        for (int j = 0; j < 4; j++) acc[i][j] = (f32x4){0.f, 0.f, 0.f, 0.f};

    const int seg = wave * 2;
    const int drow = lane >> 2;
    const int dcol = (lane & 3) * 8;
    const int sr = t >> 2, skv = t & 3;

    for (int k0 = 0; k0 < K; k0 += 32) {
#pragma unroll
        for (int c = 0; c < 2; c++) {
            const int rowA = (seg + c) * 16 + drow;
            gll16(A + (size_t)(m0 + rowA) * K + k0 + dcol, &As[(seg + c) * 512]);
        }
        if (BF16B) {
            const u16* Bh = (const u16*)Bv;
#pragma unroll
            for (int c = 0; c < 2; c++) {
                const int rowB = (seg + c) * 16 + drow;
                gll16(Bh + (size_t)(n0 + rowB) * K + k0 + dcol, &Bs[(seg + c) * 512]);
            }
        } else {
            const float* Bf = (const float*)Bv;
#pragma unroll
            for (int half = 0; half < 2; half++) {
                const float* src = Bf + (size_t)(n0 + sr + half * 64) * K + k0 + skv * 8;
                const float4 a = *(const float4*)src;
                const float4 b2 = *(const float4*)(src + 4);
                bf16x8 r;
                r[0] = (short)f2bf(a.x);  r[1] = (short)f2bf(a.y);
                r[2] = (short)f2bf(a.z);  r[3] = (short)f2bf(a.w);
                r[4] = (short)f2bf(b2.x); r[5] = (short)f2bf(b2.y);
                r[6] = (short)f2bf(b2.z); r[7] = (short)f2bf(b2.w);
                *(bf16x8*)&Bs[(sr + half * 64) * 32 + skv * 8] = r;
            }
        }
        __syncthreads();
        bf16x8 af[4], bfr[4];
#pragma unroll
        for (int i = 0; i < 4; i++)
            af[i] = *(const bf16x8*)&As[(wm * 64 + i * 16 + mr) * 32 + quad * 8];
#pragma unroll
        for (int j = 0; j < 4; j++)
            bfr[j] = *(const bf16x8*)&Bs[(wn * 64 + j * 16 + mr) * 32 + quad * 8];
#pragma unroll
        for (int i = 0; i < 4; i++)
#pragma unroll
            for (int j = 0; j < 4; j++)
                acc[i][j] = MFMA_BF16(af[i], bfr[j], acc[i][j]);
        __syncthreads();
    }

#pragma unroll
    for (int i = 0; i < 4; i++) {
#pragma unroll
        for (int r = 0; r < 4; r++) {
            const int m = m0 + wm * 64 + i * 16 + quad * 4 + r;
#pragma unroll
            for (int j = 0; j < 4; j++) {
                const int n = n0 + wn * 64 + j * 16 + mr;
                float v = acc[i][j][r] + bias[n];
                if (EPI == 1) {
                    v = gelu_fast(v);
                    ((u16*)Cv)[(size_t)m * N + n] = f2bf(v);
                } else if (EPI == 2) {
                    v += res[(size_t)m * N + n];
                    ((float*)Cv)[(size_t)m * N + n] = v;
                } else {  // EPI == 3: qkv split
                    if (n < 1536) {
                        const float vq = (n < 768) ? v * QSCALE : v;
                        ((u16*)Cv)[(size_t)m * 1536 + n] = f2bf(vq);
                    } else {
                        const int h = (n - 1536) >> 6, hd = (n - 1536) & 63;
                        const int bb = m >> 10, pos = m & 1023;
                        vtb[((size_t)(bb * 12 + h) * 64 + hd) * 1024 + pos] = f2bf(v);
                    }
                }
            }
        }
    }
}

// ---------------------------------------------------------------------------
// gemm8: NT GEMM, 256 x (NSLOT*64) tile, BK=64, 8 waves (2M x 4N), dbuf LDS,
// free-flow compute + 2 barriers/K-tile, counted vmcnt, T2 swizzle,
// XCD-chunked block swizzle.
// Per-tile: [regA: stage b2..b_{NSLOT-1},a1,a3(kt+1)->dead buf; compute]
//   lgkmcnt(0); seal-bar; [regB: stage a0,a2,b0,b1(kt+2)->cur buf];
//   vmcnt(4) (tail: 0); end-bar.
// EPI 1/2: operands swapped (bfv,af) -> C^T fragment -> vectorized stores.
// EPI 3: original order + split epilogues (q/k scalar, V LDS-transpose).
// Requires K % 64 == 0, K >= 128, M % 256 == 0, N % (NSLOT*64) == 0,
// grid % 8 == 0.
// ---------------------------------------------------------------------------
#define AFRAG(T, ROW, KS) \
    (*(const bf16x8*)&(T)[(ROW)][(((((KS) << 2) | quad)) ^ ((ROW) & 7)) << 3])

#define ACCUM(ACCEL, AF, BF)                                  \
    do {                                                      \
        if (EPI == 3) (ACCEL) = MFMA_BF16((AF), (BF), (ACCEL)); \
        else          (ACCEL) = MFMA_BF16((BF), (AF), (ACCEL)); \
    } while (0)

template <int EPI, int NSLOT>
__global__ __launch_bounds__(512, 2) void gemm8(
        const u16* __restrict__ A, const u16* __restrict__ Bw,
        const float* __restrict__ bias, const float* __restrict__ res,
        void* __restrict__ Cv, u16* __restrict__ vtb, int N, int K) {
    constexpr int TN = NSLOT * 64;
    __shared__ __align__(16) u16 SMEM[(512 + 2 * TN) * 64];
    u16(&As)[2][256][64] = *reinterpret_cast<u16(*)[2][256][64]>(&SMEM[0]);
    u16(&Bs)[2][TN][64] = *reinterpret_cast<u16(*)[2][TN][64]>(&SMEM[512 * 64]);
    const int t = threadIdx.x;
    const int wave = t >> 6, lane = t & 63;
    const int quad = lane >> 4, mr = lane & 15;
    const int wm = wave >> 2, wn = wave & 3;
    // XCD-chunked bijective swizzle: consecutive remapped ids share the A panel
    const int gx = gridDim.x;
    const int nwg = gx * gridDim.y;
    int bid = blockIdx.y * gx + blockIdx.x;
    bid = (bid & 7) * (nwg >> 3) + (bid >> 3);
    const int m0 = (bid / gx) * 256, n0 = (bid % gx) * TN;
    const int NT = K >> 6;

    const int srow = wave * 8 + (lane >> 3);          // row within 64-row slot
    const int sgrp = ((lane & 7) ^ (lane >> 3)) * 8;  // pre-swizzled src col

    const u16* Abase = A + (size_t)(m0 + srow) * K + sgrp;
    const u16* Bbase = Bw + (size_t)(n0 + srow) * K + sgrp;

#define STAGE_A(BI, SLOT, KT) \
    gll16(Abase + ((size_t)(SLOT) * 64) * K + (KT) * 64, &As[BI][(SLOT) * 64 + wave * 8][0])
#define STAGE_B(BI, SLOT, KT) \
    gll16(Bbase + ((size_t)(SLOT) * 64) * K + (KT) * 64, &Bs[BI][(SLOT) * 64 + wave * 8][0])

    // prologue: tile0 all slots -> buf0, then tile1 {a0,a2,b0,b1} -> buf1
    STAGE_A(0, 0, 0); STAGE_A(0, 1, 0); STAGE_A(0, 2, 0); STAGE_A(0, 3, 0);
#pragma unroll
    for (int s = 0; s < NSLOT; s++) STAGE_B(0, s, 0);
    if (NT > 1) { STAGE_A(1, 0, 1); STAGE_A(1, 2, 1); STAGE_B(1, 0, 1); STAGE_B(1, 1, 1); }

    f32x4 acc[8][NSLOT];
#pragma unroll
    for (int i = 0; i < 8; i++)
#pragma unroll
        for (int j = 0; j < NSLOT; j++) acc[i][j] = (f32x4){0.f, 0.f, 0.f, 0.f};

    if (NT > 1) { WAITV(4); } else { WAITV(0); }  // tile0's slots landed
    __builtin_amdgcn_s_barrier();
    SCHED0;

    for (int kt = 0; kt < NT; ++kt) {
        const int bi = kt & 1;
        const u16(*Ab)[64] = As[bi];
        const u16(*Bb)[64] = Bs[bi];
        const bool st1 = (kt + 1 < NT);
        const bool st2 = (kt + 2 < NT);

        // region A: early stages into the dead buffer, then free-flow compute
        if (st1) {
#pragma unroll
            for (int s = 2; s < NSLOT; s++) STAGE_B(bi ^ 1, s, kt + 1);
            STAGE_A(bi ^ 1, 1, kt + 1); STAGE_A(bi ^ 1, 3, kt + 1);
        }

        bf16x8 af[4], bfv[NSLOT];
        // ks = 0
#pragma unroll
        for (int j = 0; j < NSLOT; j++) bfv[j] = AFRAG(Bb, wn * (NSLOT * 16) + j * 16 + mr, 0);
#pragma unroll
        for (int i = 0; i < 4; i++) af[i] = AFRAG(Ab, wm * 128 + i * 16 + mr, 0);
#pragma unroll
        for (int i = 0; i < 4; i++)
#pragma unroll
            for (int j = 0; j < NSLOT; j++) ACCUM(acc[i][j], af[i], bfv[j]);
#pragma unroll
        for (int i = 0; i < 4; i++) af[i] = AFRAG(Ab, wm * 128 + 64 + i * 16 + mr, 0);
#pragma unroll
        for (int i = 0; i < 4; i++)
#pragma unroll
            for (int j = 0; j < NSLOT; j++) ACCUM(acc[4 + i][j], af[i], bfv[j]);
        // ks = 1
#pragma unroll
        for (int j = 0; j < NSLOT; j++) bfv[j] = AFRAG(Bb, wn * (NSLOT * 16) + j * 16 + mr, 1);
#pragma unroll
        for (int i = 0; i < 4; i++) af[i] = AFRAG(Ab, wm * 128 + i * 16 + mr, 1);
#pragma unroll
        for (int i = 0; i < 4; i++)
#pragma unroll
            for (int j = 0; j < NSLOT; j++) ACCUM(acc[i][j], af[i], bfv[j]);
#pragma unroll
        for (int i = 0; i < 4; i++) af[i] = AFRAG(Ab, wm * 128 + 64 + i * 16 + mr, 1);
#pragma unroll
        for (int i = 0; i < 4; i++)
#pragma unroll
            for (int j = 0; j < NSLOT; j++) ACCUM(acc[4 + i][j], af[i], bfv[j]);

        WAITLGKM0;  // cheap: MFMAs already consumed all reads
        SCHED0;
        __builtin_amdgcn_s_barrier();  // seal: cur-buf slots a0,a2,b0,b1 free
        SCHED0;
        if (st2) { STAGE_A(bi, 0, kt + 2); STAGE_A(bi, 2, kt + 2);
                   STAGE_B(bi, 0, kt + 2); STAGE_B(bi, 1, kt + 2); }
        SCHED0;
        if (st2) { WAITV(4); } else { WAITV(0); }  // retire kt+1's slots
        __builtin_amdgcn_s_barrier();              // publish kt+1
        SCHED0;
    }

    if (EPI == 3) {
        if (n0 >= 1536) {
            // V-epilogue: LDS transpose (Ls[n_local][m swizzled]) -> coalesced vtb
            u16* Ls = &SMEM[0];  // [TN n][256 m]
            __syncthreads();
#pragma unroll
            for (int i = 0; i < 8; i++) {
                const int mbase = wm * 128 + (i >> 2) * 64 + (i & 3) * 16 + quad * 4;
                const int mch = mbase >> 3, mlo = mbase & 7;  // mlo in {0,4}
#pragma unroll
                for (int j = 0; j < NSLOT; j++) {
                    const int nl = wn * (NSLOT * 16) + j * 16 + mr;
                    float v0 = acc[i][j][0] + bias[n0 + nl];
                    float v1 = acc[i][j][1] + bias[n0 + nl];
                    float v2 = acc[i][j][2] + bias[n0 + nl];
                    float v3 = acc[i][j][3] + bias[n0 + nl];
                    ushort4 w;
                    w.x = f2bf(v0); w.y = f2bf(v1); w.z = f2bf(v2); w.w = f2bf(v3);
                    *(ushort4*)(Ls + nl * 256 + ((mch ^ (nl & 7)) << 3) + mlo) = w;
                }
            }
            __syncthreads();
            const int bb = m0 >> 10, pos0 = m0 & 1023;
#pragma unroll
            for (int it = 0; it < TN / 8; it++) {
                const int nl = it * 8 + wave;  // wave-uniform column
                const int h = (n0 - 1536 + nl) >> 6;
                const int hd = nl & 63;        // (n0-1536) % 64 == 0
                const int mch = (lane >> 1) ^ (nl & 7);
                const ushort4 v =
                    *(const ushort4*)(Ls + nl * 256 + (mch << 3) + (lane & 1) * 4);
                u16* dst = vtb + ((size_t)(bb * 12 + h) * 64 + hd) * 1024 + pos0 + lane * 4;
                *(ushort4*)dst = v;  // 512B contiguous per wave
            }
        } else {
            // q/k region: original scalar epilogue (r = m-direction)
#pragma unroll
            for (int i = 0; i < 8; i++) {
#pragma unroll
                for (int r = 0; r < 4; r++) {
                    const int m = m0 + wm * 128 + (i >> 2) * 64 + (i & 3) * 16 + quad * 4 + r;
#pragma unroll
                    for (int j = 0; j < NSLOT; j++) {
                        const int n = n0 + wn * (NSLOT * 16) + j * 16 + mr;
                        float v = acc[i][j][r] + bias[n];
                        const float vq = (n < 768) ? v * QSCALE : v;
                        ((u16*)Cv)[(size_t)m * 1536 + n] = f2bf(vq);
                    }
                }
            }
        }
    } else {
        // swapped fragment: lane holds n..n+3 (reg r) at fixed m
#pragma unroll
        for (int ii = 0; ii < 8; ii++) {
            const int m = m0 + wm * 128 + (ii >> 2) * 64 + (ii & 3) * 16 + mr;
#pragma unroll
            for (int j = 0; j < NSLOT; j++) {
                const int n = n0 + wn * (NSLOT * 16) + j * 16 + quad * 4;
                const float4 b4 = *(const float4*)&bias[n];
                const float v0 = acc[ii][j][0] + b4.x;
                const float v1 = acc[ii][j][1] + b4.y;
                const float v2 = acc[ii][j][2] + b4.z;
                const float v3 = acc[ii][j][3] + b4.w;
                if (EPI == 1) {
                    ushort4 w;
                    w.x = f2bf(gelu_fast(v0)); w.y = f2bf(gelu_fast(v1));
                    w.z = f2bf(gelu_fast(v2)); w.w = f2bf(gelu_fast(v3));
                    *(ushort4*)&((u16*)Cv)[(size_t)m * N + n] = w;
                } else {  // EPI == 2
                    const float4 r4 = *(const float4*)&res[(size_t)m * N + n];
                    float4 o;
                    o.x = v0 + r4.x; o.y = v1 + r4.y; o.z = v2 + r4.z; o.w = v3 + r4.w;
                    *(float4*)&((float*)Cv)[(size_t)m * N + n] = o;
                }
            }
        }
    }
#undef STAGE_A
#undef STAGE_B
}

// ---------------------------------------------------------------------------
// Flash attention v2. Block = (b,h) x 128 q-rows, 8 waves x 16 rows.
// qkkb [M][1536]: q(pre-scaled QSCALE=0.125*log2e) @0, k @768.
// vtb [b*12+h][64 hd][1024].
// Swapped-operand MFMA; exp2 softmax; cvt_pk P pack; O^T fragment.
// 512 threads stage one 64-row K/V tile (2 loads/thread); staging per Q-row
// halves vs QBLK=64. LDS 55KB -> 2 blocks/CU = 4 waves/SIMD.
// XCD remap: dispatch-linear L, xcd=L&7 -> bh in [xcd*24, xcd*24+24).
// ---------------------------------------------------------------------------
__global__ __launch_bounds__(512) void attn2(const u16* __restrict__ qkkb,
                                             const u16* __restrict__ vtb,
                                             u16* __restrict__ ctx) {
    __shared__ __align__(16) u16 Ks[2][64][72];
    __shared__ __align__(16) u16 Vt[2][64][72];
    __shared__ __align__(16) u16 Ps[128][72];
    const int L = blockIdx.y * gridDim.x + blockIdx.x;  // dispatch-linear
    const int lxcd = L & 7, li = L >> 3;                // li in [0,192)
    const int bh = lxcd * 24 + (li >> 3);
    const int q0 = (li & 7) * 128;
    const int b = bh / 12, h = bh % 12;
    const int t = threadIdx.x;
    const int wave = t >> 6, lane = t & 63, quad = lane >> 4, mr = lane & 15;

    const u16* qrow = qkkb + (size_t)(b * 1024 + q0 + wave * 16 + mr) * 1536 + h * 64;
    const bf16x8 qf0 = *(const bf16x8*)(qrow + quad * 8);
    const bf16x8 qf1 = *(const bf16x8*)(qrow + 32 + quad * 8);

    const u16* kbase = qkkb + (size_t)b * 1024 * 1536 + 768 + h * 64;
    const u16* vbase = vtb + (size_t)bh * 64 * 1024;

    const int srow = t >> 3;  // 0..63 (full tile, 512 threads)
    const int sv = t & 7;     // 16B chunk

    f32x4 oacc[4];
#pragma unroll
    for (int j = 0; j < 4; j++) oacc[j] = (f32x4){0.f, 0.f, 0.f, 0.f};
    float lsum = 0.f;  // q = mr, kv subset = lane's quads

    bf16x8 pk0, pv0;
    pk0 = *(const bf16x8*)(kbase + (size_t)srow * 1536 + sv * 8);
    pv0 = *(const bf16x8*)(vbase + (size_t)srow * 1024 + sv * 8);
    *(bf16x8*)&Ks[0][srow][sv * 8] = pk0;
    *(bf16x8*)&Vt[0][srow][sv * 8] = pv0;

    for (int kt = 0; kt < 16; ++kt) {
        __syncthreads();
        const int cur = kt & 1;
        if (kt < 15) {
            const size_t ko = (size_t)(kt + 1) * 64;
            pk0 = *(const bf16x8*)(kbase + (ko + srow) * 1536 + sv * 8);
            pv0 = *(const bf16x8*)(vbase + (size_t)srow * 1024 + ko + sv * 8);
        }
        // S^T = K Q^T: lane holds S[q=mr][kv=j*16+quad*4+r] (scale in Q)
        f32x4 sf[4];
#pragma unroll
        for (int j = 0; j < 4; j++) {
            const bf16x8 kf0 = *(const bf16x8*)&Ks[cur][j * 16 + mr][quad * 8];
            const bf16x8 kf1 = *(const bf16x8*)&Ks[cur][j * 16 + mr][32 + quad * 8];
            f32x4 s = (f32x4){0.f, 0.f, 0.f, 0.f};
            s = MFMA_BF16(kf0, qf0, s);
            s = MFMA_BF16(kf1, qf1, s);
            sf[j] = s;
        }
        // p = exp2(s' - 8*log2e) == exp(s - 8); pack pairs, 1 b64 write per j
#pragma unroll
        for (int j = 0; j < 4; j++) {
            const float p0 = EXP2F(sf[j][0] - C8LOG2E);
            const float p1 = EXP2F(sf[j][1] - C8LOG2E);
            const float p2 = EXP2F(sf[j][2] - C8LOG2E);
            const float p3 = EXP2F(sf[j][3] - C8LOG2E);
            lsum += (p0 + p1) + (p2 + p3);
            uint2 w;
            w.x = cvtpk_bf16(p0, p1);
            w.y = cvtpk_bf16(p2, p3);
            *(uint2*)&Ps[wave * 16 + mr][j * 16 + quad * 4] = w;
        }
        __asm__ __volatile__("s_waitcnt lgkmcnt(0)" ::: "memory");  // wave-local Ps RAW
        // O^T += V P^T  (A = V^T rows=d, B = P rows=q)
#pragma unroll
        for (int st = 0; st < 2; st++) {
            const bf16x8 pf = *(const bf16x8*)&Ps[wave * 16 + mr][st * 32 + quad * 8];
#pragma unroll
            for (int j = 0; j < 4; j++) {
                const bf16x8 vf = *(const bf16x8*)&Vt[cur][j * 16 + mr][st * 32 + quad * 8];
                oacc[j] = MFMA_BF16(vf, pf, oacc[j]);
            }
        }
        if (kt < 15) {
            const int nxt = cur ^ 1;
            *(bf16x8*)&Ks[nxt][srow][sv * 8] = pk0;
            *(bf16x8*)&Vt[nxt][srow][sv * 8] = pv0;
        }
    }

    // lsum: reduce across the 4 quads (same q=mr)
    lsum += __shfl_xor(lsum, 16);
    lsum += __shfl_xor(lsum, 32);
    const float inv = 1.0f / lsum;
    // lane holds O[d=j*16+quad*4+r][q=mr]: 4 contiguous d per j -> ushort4
    u16* dst = ctx + (size_t)(b * 1024 + q0 + wave * 16 + mr) * 768 + h * 64;
#pragma unroll
    for (int j = 0; j < 4; j++) {
        ushort4 w;
        w.x = f2bf(oacc[j][0] * inv);
        w.y = f2bf(oacc[j][1] * inv);
        w.z = f2bf(oacc[j][2] * inv);
        w.w = f2bf(oacc[j][3] * inv);
        *(ushort4*)(dst + j * 16 + quad * 4) = w;
    }
}

// ---------------------------------------------------------------------------
// Launcher. ws layout (bytes), base = d_ws + 1024:
//   xn/ctxb/hn @ +0         (25165824)
//   qkkb       @ +25165824  (50331648)  } h1 (100663296) overlays both
//   vtb        @ +75497472  (25165824)  } (dead after attention)
// bf16 weights (14155776 B) appended iff ws_size >= 139,985,920; else the
// GEMMs fall back to in-staging fp32->bf16 B casts (gemm2 path).
// ---------------------------------------------------------------------------
extern "C" void kernel_launch(void* const* d_in, const int* in_sizes, int n_in,
                              void* d_out, int out_size, void* d_ws, size_t ws_size,
                              hipStream_t stream) {
    const float* x      = (const float*)d_in[0];
    const float* ln1_g  = (const float*)d_in[1];
    const float* ln1_b  = (const float*)d_in[2];
    const float* qkv_w  = (const float*)d_in[3];
    const float* qkv_b  = (const float*)d_in[4];
    const float* proj_w = (const float*)d_in[5];
    const float* proj_b = (const float*)d_in[6];
    const float* ln2_g  = (const float*)d_in[7];
    const float* ln2_b  = (const float*)d_in[8];
    const float* fc1_w  = (const float*)d_in[9];
    const float* fc1_b  = (const float*)d_in[10];
    const float* fc2_w  = (const float*)d_in[11];
    const float* fc2_b  = (const float*)d_in[12];
    float* out = (float*)d_out;

    char* base = (char*)d_ws + 1024;
    u16* xn   = (u16*)base;                  // reused: ctxb, hn
    u16* qkkb = (u16*)(base + 25165824);
    u16* vtb  = (u16*)(base + 75497472);
    u16* h1   = (u16*)(base + 25165824);     // overlays qkkb+vtb
    u16* ctxb = xn;
    u16* hn   = xn;

    const size_t WOFF = 125830144ull;
    const bool big = ws_size >= 139985920ull;
    u16* wqkv  = (u16*)((char*)d_ws + WOFF);
    u16* wproj = (u16*)((char*)d_ws + WOFF + 3538944);
    u16* wfc1  = (u16*)((char*)d_ws + WOFF + 4718592);
    u16* wfc2  = (u16*)((char*)d_ws + WOFF + 9437184);

    if (big) {
        cast32<<<dim3(864),  dim3(256), 0, stream>>>(qkv_w,  wqkv,  221184);
        cast32<<<dim3(288),  dim3(256), 0, stream>>>(proj_w, wproj, 73728);
        cast32<<<dim3(1152), dim3(256), 0, stream>>>(fc1_w,  wfc1,  294912);
        cast32<<<dim3(1152), dim3(256), 0, stream>>>(fc2_w,  wfc2,  294912);
    }

    ln_kernel<<<dim3(16384), dim3(256), 0, stream>>>(x, ln1_g, ln1_b, xn);

    if (big)
        gemm8<3, 3><<<dim3(12, 64), dim3(512), 0, stream>>>(
            xn, wqkv, qkv_b, nullptr, qkkb, vtb, 2304, 768);
    else
        gemm2<3, 0><<<dim3(18, 128), dim3(256), 0, stream>>>(
            xn, qkv_w, qkv_b, nullptr, qkkb, vtb, 2304, 768);

    attn2<<<dim3(8, 192), dim3(512), 0, stream>>>(qkkb, vtb, ctxb);

    if (big)
        gemm8<2, 3><<<dim3(4, 64), dim3(512), 0, stream>>>(
            ctxb, wproj, proj_b, x, out, nullptr, 768, 768);
    else
        gemm2<2, 0><<<dim3(6, 128), dim3(256), 0, stream>>>(
            ctxb, proj_w, proj_b, x, out, nullptr, 768, 768);

    ln_kernel<<<dim3(16384), dim3(256), 0, stream>>>(out, ln2_g, ln2_b, hn);

    if (big)
        gemm8<1, 4><<<dim3(12, 64), dim3(512), 0, stream>>>(
            hn, wfc1, fc1_b, nullptr, h1, nullptr, 3072, 768);
    else
        gemm2<1, 0><<<dim3(24, 128), dim3(256), 0, stream>>>(
            hn, fc1_w, fc1_b, nullptr, h1, nullptr, 3072, 768);

    if (big)
        gemm8<2, 3><<<dim3(4, 64), dim3(512), 0, stream>>>(
            h1, wfc2, fc2_b, out, out, nullptr, 768, 3072);
    else
        gemm2<2, 0><<<dim3(6, 128), dim3(256), 0, stream>>>(
            h1, fc2_w, fc2_b, out, out, nullptr, 768, 3072);
}